// Round 9
// baseline (452.660 us; speedup 1.0000x reference)
//
#include <hip/hip_runtime.h>

typedef unsigned short u16;
typedef __bf16 bf16x8 __attribute__((ext_vector_type(8)));
typedef __bf16 bf16x2_t __attribute__((ext_vector_type(2)));
typedef float f32x4 __attribute__((ext_vector_type(4)));

__device__ __forceinline__ u16 f2bf(float f) {
  union { float f; unsigned int u; } v; v.f = f;
  unsigned int u = v.u;
  u += 0x7fffu + ((u >> 16) & 1u);
  return (u16)(u >> 16);
}
__device__ __forceinline__ float bf2f(u16 h) {
  union { unsigned int u; float f; } v; v.u = ((unsigned int)h) << 16; return v.f;
}
// pack 2 fp32 -> 2 bf16 in one HW instr where available
__device__ __forceinline__ unsigned int pk2(float a, float b) {
#if __has_builtin(__builtin_amdgcn_cvt_pk_bf16_f32)
  union { bf16x2_t v; unsigned int u; } c;
  c.v = __builtin_amdgcn_cvt_pk_bf16_f32(a, b);
  return c.u;
#else
  return (unsigned int)f2bf(a) | ((unsigned int)f2bf(b) << 16);
#endif
}
// fast GELU: v * sigmoid(v*(1.5957691 + 0.0713548*v^2)); raw v_rcp (1 instr)
__device__ __forceinline__ float gelu_f(float v) {
  float u = v * (1.5957691216f + 0.0713548163f * v * v);
  return v * __builtin_amdgcn_rcpf(1.0f + __expf(-u));
}

// ---------------- cast weights fp32 -> bf16 ----------------
// proj_w gets head-interleaved column permutation to match attn's packed stores:
// attn lane holds (d, d+16) pairs -> stored at cols (2d, 2d+1) within the head.
__global__ __launch_bounds__(256) void cast_weights(
    const float* __restrict__ w0, const float* __restrict__ w1,
    const float* __restrict__ w2, const float* __restrict__ w3,
    u16* __restrict__ o0, u16* __restrict__ o1,
    u16* __restrict__ o2, u16* __restrict__ o3) {
  int i = blockIdx.x * 256 + threadIdx.x;
  if (i < 110592) o0[i] = f2bf(w0[i]);   // qkv_w 576x192
  if (i < 36864) {                        // proj_w 192x192, k-permuted
    int n = i / 192, kp = i - n * 192;
    int h = kp >> 5, dp = kp & 31;
    int d = (dp & 1) ? ((dp >> 1) + 16) : (dp >> 1);
    o1[i] = f2bf(w1[n * 192 + h * 32 + d]);
  }
  if (i < 221184) o2[i] = f2bf(w2[i]);   // fc1_w 1152x192
  if (i < 221184) o3[i] = f2bf(w3[i]);   // fc2_w 192x1152
}

// ---------------- bias table [6][64(key m)][64(query r)]; key>=49 -> -1e30 ----
__global__ __launch_bounds__(256) void build_btab(
    const float* __restrict__ rpb, float* __restrict__ btab) {
  int id = blockIdx.x * 256 + threadIdx.x;   // 96*256 = 24576
  int head = id >> 12;
  int m = (id >> 6) & 63;
  int r = id & 63;
  float v;
  if (m >= 49) v = -1e30f;                   // key mask folds into bias
  else if (r >= 49) v = 0.0f;
  else {
    int mi = m / 7, mj = m - mi * 7;
    int ri = r / 7, rj = r - ri * 7;
    v = rpb[((ri - mi + 6) * 13 + (rj - mj + 6)) * 6 + head];
  }
  btab[id] = v;
}

// ---------------- layernorm (fp32 in, bf16 out), 1 wave per row of 192 ----------------
__global__ __launch_bounds__(256) void ln_kernel(
    const float* __restrict__ x, const float* __restrict__ g,
    const float* __restrict__ b, u16* __restrict__ out) {
  int row = blockIdx.x * 4 + (threadIdx.x >> 6);
  int lane = threadIdx.x & 63;
  const float* xr = x + (long)row * 192;
  float e0 = xr[lane], e1 = xr[lane + 64], e2 = xr[lane + 128];
  float s = e0 + e1 + e2;
  #pragma unroll
  for (int o = 1; o < 64; o <<= 1) s += __shfl_xor(s, o);
  float mean = s * (1.0f / 192.0f);
  float d0 = e0 - mean, d1 = e1 - mean, d2 = e2 - mean;
  float q = d0 * d0 + d1 * d1 + d2 * d2;
  #pragma unroll
  for (int o = 1; o < 64; o <<= 1) q += __shfl_xor(q, o);
  float rstd = rsqrtf(q * (1.0f / 192.0f) + 1e-5f);
  u16* orow = out + (long)row * 192;
  orow[lane]       = f2bf(d0 * rstd * g[lane]       + b[lane]);
  orow[lane + 64]  = f2bf(d1 * rstd * g[lane + 64]  + b[lane + 64]);
  orow[lane + 128] = f2bf(d2 * rstd * g[lane + 128] + b[lane + 128]);
}

// ---------------- MFMA GEMM, direct-register operands (no LDS in K-loop) -----
// out[M,N] = A[M,K] @ W[N,K]^T + bias. Block 128x96, 4 waves 2x2, wave 64x48.
// MFMA fragments (16 B/lane, k-contiguous) are loaded STRAIGHT from global
// into registers — no LDS staging, no __syncthreads in the K-loop, register
// double-buffer (chunk c+1 loads issued before chunk c's MFMAs). K is a
// template arg so the loop fully unrolls and the compiler pipelines loads as
// deep as the VGPR budget allows. Wave-pair line reuse is served by L1/L2.
// LDS only for the coalescing epilogue (64x100 fp32, 25.6 KB).
// MODE 0: store bf16. MODE 1: fast-GELU -> bf16. MODE 2: +resid(fp32) -> fp32.
// Requires N % 96 == 0, M % 128 == 0, K % 32 == 0.
template<int MODE, int K>
__global__ __launch_bounds__(256, 3) void gemm_kernel(
    const u16* __restrict__ A, const u16* __restrict__ W,
    const float* __restrict__ bias, const float* __restrict__ resid,
    void* __restrict__ out, int N) {
  __shared__ float ct[64 * 100];       // epilogue only
  const int tid = threadIdx.x;
  const int wave = tid >> 6, lane = tid & 63;
  const int wm = wave >> 1, wn = wave & 1;
  const int quad = lane >> 4, l15 = lane & 15;
  const long bm = (long)blockIdx.x * 128;
  const int bn = blockIdx.y * 96;
  constexpr int NC = K / 32;

  const u16* Ab = A + (bm + wm * 64 + l15) * K + quad * 8;
  const u16* Wb = W + (long)(bn + wn * 48 + l15) * K + quad * 8;

  bf16x8 af[2][4], bfr[2][3];
  #pragma unroll
  for (int mt = 0; mt < 4; mt++)
    af[0][mt] = *(const bf16x8*)(Ab + (long)mt * 16 * K);
  #pragma unroll
  for (int nt = 0; nt < 3; nt++)
    bfr[0][nt] = *(const bf16x8*)(Wb + (long)nt * 16 * K);

  f32x4 acc[4][3] = {};
  #pragma unroll
  for (int c = 0; c < NC; c++) {
    const int cur = c & 1, nxt = cur ^ 1;
    if (c + 1 < NC) {
      const int kof = (c + 1) * 32;
      #pragma unroll
      for (int mt = 0; mt < 4; mt++)
        af[nxt][mt] = *(const bf16x8*)(Ab + (long)mt * 16 * K + kof);
      #pragma unroll
      for (int nt = 0; nt < 3; nt++)
        bfr[nxt][nt] = *(const bf16x8*)(Wb + (long)nt * 16 * K + kof);
    }
    #pragma unroll
    for (int mt = 0; mt < 4; mt++)
      #pragma unroll
      for (int nt = 0; nt < 3; nt++)
        acc[mt][nt] = __builtin_amdgcn_mfma_f32_16x16x32_bf16(af[cur][mt], bfr[cur][nt], acc[mt][nt], 0, 0, 0);
  }

  // ---- epilogue: two 64-row passes through LDS -> coalesced line stores ----
  #pragma unroll
  for (int h = 0; h < 2; h++) {
    if (wm == h) {
      #pragma unroll
      for (int nt = 0; nt < 3; nt++) {
        int col = wn * 48 + nt * 16 + l15;
        float bi = bias[bn + col];
        #pragma unroll
        for (int mt = 0; mt < 4; mt++) {
          int row0 = mt * 16 + quad * 4;
          #pragma unroll
          for (int j = 0; j < 4; j++)
            ct[(row0 + j) * 100 + col] = acc[mt][nt][j] + bi;
        }
      }
    }
    __syncthreads();
    // 64 rows x 24 float4-groups = 1536 chunks, 6 per thread
    #pragma unroll
    for (int it = 0; it < 6; it++) {
      int cc = it * 256 + tid;
      int row = cc / 24, i = cc - row * 24;
      float4 v = *(const float4*)&ct[row * 100 + i * 4];
      long idx = (bm + h * 64 + row) * (long)N + bn + i * 4;
      if (MODE == 2) {
        const float4 rv = *(const float4*)(resid + idx);
        v.x += rv.x; v.y += rv.y; v.z += rv.z; v.w += rv.w;
        *(float4*)((float*)out + idx) = v;
      } else {
        if (MODE == 1) {
          v.x = gelu_f(v.x); v.y = gelu_f(v.y); v.z = gelu_f(v.z); v.w = gelu_f(v.w);
        }
        uint2 pk;
        pk.x = pk2(v.x, v.y);
        pk.y = pk2(v.z, v.w);
        *(uint2*)((u16*)out + idx) = pk;
      }
    }
    if (h == 0) __syncthreads();
  }
}

// ---------------- MFMA windowed attention: 1 wave per (window, head) ----------------
__global__ __launch_bounds__(256) void attn_kernel(
    const u16* __restrict__ qkv, const float* __restrict__ btab,
    u16* __restrict__ attn) {
  // per-wave u16: P 64x72 = 4608 | Vt 32x72 = 2304 | rsum 64 f32 = 128
  __shared__ u16 lds[4 * 7040];   // 56,320 B
  int tid = threadIdx.x;
  int wave = tid >> 6, lane = tid & 63;
  int quad = lane >> 4, l15 = lane & 15;
  int w = blockIdx.x * 4 + wave;
  int win = w / 6, head = w - win * 6;
  int b = win >> 6, wy = (win >> 3) & 7, wx = win & 7;
  u16* lp = lds + wave * 7040;
  u16* lvt = lp + 4608;
  float* rsum = (float*)(lp + 6912);

  bf16x8 qb[4], ka[4];
  #pragma unroll
  for (int t = 0; t < 4; t++) {
    int n = t * 16 + l15;
    uint4 qv = {0, 0, 0, 0}, kv = {0, 0, 0, 0}, vv = {0, 0, 0, 0};
    if (n < 49) {
      int i = n / 7, j = n - i * 7;
      int y = wy * 7 + i + 3;  if (y >= 56) y -= 56;
      int xx = wx * 7 + j + 3; if (xx >= 56) xx -= 56;
      long base = ((long)(b * 3136 + y * 56 + xx)) * 576 + head * 32 + quad * 8;
      qv = *(const uint4*)(qkv + base);
      kv = *(const uint4*)(qkv + base + 192);
      vv = *(const uint4*)(qkv + base + 384);
    }
    qb[t] = *(const bf16x8*)&qv;
    ka[t] = *(const bf16x8*)&kv;
    const u16* vp = (const u16*)&vv;
    #pragma unroll
    for (int d = 0; d < 8; d++) lvt[(quad * 8 + d) * 72 + n] = vp[d];
  }

  f32x4 s[4][4];
  const f32x4 fz = {0.0f, 0.0f, 0.0f, 0.0f};
  #pragma unroll
  for (int tm = 0; tm < 4; tm++)
    #pragma unroll
    for (int tr = 0; tr < 4; tr++)
      s[tm][tr] = __builtin_amdgcn_mfma_f32_16x16x32_bf16(ka[tm], qb[tr], fz, 0, 0, 0);

  const float scale = 0.17677669529663687f;  // 32^-0.5
  const float* bt = btab + head * 4096;
  float mx[4] = {-1e30f, -1e30f, -1e30f, -1e30f};
  #pragma unroll
  for (int tm = 0; tm < 4; tm++) {
    int m0 = tm * 16 + quad * 4;
    #pragma unroll
    for (int tr = 0; tr < 4; tr++) {
      int r = tr * 16 + l15;
      #pragma unroll
      for (int j = 0; j < 4; j++) {
        float v = s[tm][tr][j] * scale + bt[(m0 + j) * 64 + r];
        s[tm][tr][j] = v;
        mx[tr] = fmaxf(mx[tr], v);
      }
    }
  }
  #pragma unroll
  for (int tr = 0; tr < 4; tr++) {
    mx[tr] = fmaxf(mx[tr], __shfl_xor(mx[tr], 16));
    mx[tr] = fmaxf(mx[tr], __shfl_xor(mx[tr], 32));
  }
  float sm[4] = {0.f, 0.f, 0.f, 0.f};
  #pragma unroll
  for (int tm = 0; tm < 4; tm++) {
    #pragma unroll
    for (int tr = 0; tr < 4; tr++) {
      int r = tr * 16 + l15;
      float e0 = __expf(s[tm][tr][0] - mx[tr]);
      float e1 = __expf(s[tm][tr][1] - mx[tr]);
      float e2 = __expf(s[tm][tr][2] - mx[tr]);
      float e3 = __expf(s[tm][tr][3] - mx[tr]);
      sm[tr] += (e0 + e1) + (e2 + e3);
      uint2 pk;
      pk.x = pk2(e0, e1);
      pk.y = pk2(e2, e3);
      *(uint2*)&lp[r * 72 + tm * 16 + quad * 4] = pk;
    }
  }
  #pragma unroll
  for (int tr = 0; tr < 4; tr++) {
    sm[tr] += __shfl_xor(sm[tr], 16);
    sm[tr] += __shfl_xor(sm[tr], 32);
  }
  if (quad == 0) {
    #pragma unroll
    for (int tr = 0; tr < 4; tr++) rsum[tr * 16 + l15] = __builtin_amdgcn_rcpf(sm[tr]);
  }

  f32x4 o[4][2] = {};
  #pragma unroll
  for (int ks = 0; ks < 2; ks++) {
    bf16x8 vb0 = *(const bf16x8*)&lvt[(l15) * 72 + ks * 32 + quad * 8];
    bf16x8 vb1 = *(const bf16x8*)&lvt[(16 + l15) * 72 + ks * 32 + quad * 8];
    #pragma unroll
    for (int rt = 0; rt < 4; rt++) {
      bf16x8 pf = *(const bf16x8*)&lp[(rt * 16 + l15) * 72 + ks * 32 + quad * 8];
      o[rt][0] = __builtin_amdgcn_mfma_f32_16x16x32_bf16(pf, vb0, o[rt][0], 0, 0, 0);
      o[rt][1] = __builtin_amdgcn_mfma_f32_16x16x32_bf16(pf, vb1, o[rt][1], 0, 0, 0);
    }
  }
  #pragma unroll
  for (int rt = 0; rt < 4; rt++) {
    #pragma unroll
    for (int j = 0; j < 4; j++) {
      int r = rt * 16 + quad * 4 + j;
      if (r < 49) {
        float inv = rsum[r];
        int i = r / 7, jj = r - i * 7;
        int y = wy * 7 + i + 3;   if (y >= 56) y -= 56;
        int xx = wx * 7 + jj + 3; if (xx >= 56) xx -= 56;
        long base = ((long)(b * 3136 + y * 56 + xx)) * 192 + head * 32 + 2 * l15;
        *(unsigned int*)&attn[base] = pk2(o[rt][0][j] * inv, o[rt][1][j] * inv);
      }
    }
  }
}

extern "C" void kernel_launch(void* const* d_in, const int* in_sizes, int n_in,
                              void* d_out, int out_size, void* d_ws, size_t ws_size,
                              hipStream_t stream) {
  (void)in_sizes; (void)n_in; (void)out_size; (void)ws_size;
  const float* x      = (const float*)d_in[0];
  const float* ln1_g  = (const float*)d_in[3];
  const float* ln1_b  = (const float*)d_in[4];
  const float* qkv_w  = (const float*)d_in[5];
  const float* qkv_b  = (const float*)d_in[6];
  const float* rpb    = (const float*)d_in[7];
  const float* proj_w = (const float*)d_in[8];
  const float* proj_b = (const float*)d_in[9];
  const float* ln2_g  = (const float*)d_in[10];
  const float* ln2_b  = (const float*)d_in[11];
  const float* fc1_w  = (const float*)d_in[12];
  const float* fc1_b  = (const float*)d_in[13];
  const float* fc2_w  = (const float*)d_in[14];
  const float* fc2_b  = (const float*)d_in[15];

  // workspace layout (bytes), M=50176:
  //   [0,            38,535,168)  x2 fp32
  //   [38,535,168,   57,802,752)  hA bf16 (ln1 out / ln2 out; btab overlays)
  //   [57,802,752,  115,605,504)  qkv bf16  --+ dead after proj; hid bf16
  //   [115,605,504, 134,873,088)  attn bf16 --+ overlays [57,802,752, ...)
  //   [173,408,256, 174,587,904)  bf16 weights
  char* ws = (char*)d_ws;
  float* x2   = (float*)(ws + 0);
  u16* hA     = (u16*)(ws + 38535168);
  float* btab = (float*)(ws + 38535168);   // live only qkv->attn
  u16* qkv    = (u16*)(ws + 57802752);
  u16* attn   = (u16*)(ws + 115605504);
  u16* hid    = (u16*)(ws + 57802752);
  u16* wbuf   = (u16*)(ws + 173408256);
  u16* qkv_wb  = wbuf;
  u16* proj_wb = wbuf + 110592;
  u16* fc1_wb  = wbuf + 147456;
  u16* fc2_wb  = wbuf + 368640;

  cast_weights<<<dim3(864), 256, 0, stream>>>(qkv_w, proj_w, fc1_w, fc2_w,
                                              qkv_wb, proj_wb, fc1_wb, fc2_wb);
  ln_kernel<<<dim3(12544), 256, 0, stream>>>(x, ln1_g, ln1_b, hA);
  gemm_kernel<0, 192><<<dim3(392, 6), 256, 0, stream>>>(hA, qkv_wb, qkv_b, nullptr,
                                                        qkv, 576);
  build_btab<<<dim3(96), 256, 0, stream>>>(rpb, btab);
  attn_kernel<<<dim3(1536), 256, 0, stream>>>(qkv, btab, attn);
  gemm_kernel<2, 192><<<dim3(392, 2), 256, 0, stream>>>(attn, proj_wb, proj_b, x,
                                                        x2, 192);
  ln_kernel<<<dim3(12544), 256, 0, stream>>>(x2, ln2_g, ln2_b, hA);
  gemm_kernel<1, 192><<<dim3(392, 12), 256, 0, stream>>>(hA, fc1_wb, fc1_b, nullptr,
                                                         hid, 1152);
  gemm_kernel<2, 1152><<<dim3(392, 2), 256, 0, stream>>>(hid, fc2_wb, fc2_b, x2,
                                                         (float*)d_out, 192);
}

// Round 10
// 359.549 us; speedup vs baseline: 1.2590x; 1.2590x over previous
//
#include <hip/hip_runtime.h>

typedef unsigned short u16;
typedef __bf16 bf16x8 __attribute__((ext_vector_type(8)));
typedef __bf16 bf16x2_t __attribute__((ext_vector_type(2)));
typedef float f32x4 __attribute__((ext_vector_type(4)));

#define AS1 __attribute__((address_space(1)))
#define AS3 __attribute__((address_space(3)))

__device__ __forceinline__ void gld16(const void* g, void* l) {
  // 16B per lane: global per-lane gather -> LDS (wave-uniform base + lane*16)
  __builtin_amdgcn_global_load_lds((const AS1 void*)g, (AS3 void*)l, 16, 0, 0);
}

__device__ __forceinline__ u16 f2bf(float f) {
  union { float f; unsigned int u; } v; v.f = f;
  unsigned int u = v.u;
  u += 0x7fffu + ((u >> 16) & 1u);
  return (u16)(u >> 16);
}
__device__ __forceinline__ float bf2f(u16 h) {
  union { unsigned int u; float f; } v; v.u = ((unsigned int)h) << 16; return v.f;
}
// pack 2 fp32 -> 2 bf16 in one HW instr where available
__device__ __forceinline__ unsigned int pk2(float a, float b) {
#if __has_builtin(__builtin_amdgcn_cvt_pk_bf16_f32)
  union { bf16x2_t v; unsigned int u; } c;
  c.v = __builtin_amdgcn_cvt_pk_bf16_f32(a, b);
  return c.u;
#else
  return (unsigned int)f2bf(a) | ((unsigned int)f2bf(b) << 16);
#endif
}
// fast GELU: v * sigmoid(v*(1.5957691 + 0.0713548*v^2)); raw v_rcp (1 instr)
__device__ __forceinline__ float gelu_f(float v) {
  float u = v * (1.5957691216f + 0.0713548163f * v * v);
  return v * __builtin_amdgcn_rcpf(1.0f + __expf(-u));
}

// ---------------- cast weights fp32 -> bf16 ----------------
// proj_w gets head-interleaved column permutation to match attn's packed stores:
// attn lane holds (d, d+16) pairs -> stored at cols (2d, 2d+1) within the head.
__global__ __launch_bounds__(256) void cast_weights(
    const float* __restrict__ w0, const float* __restrict__ w1,
    const float* __restrict__ w2, const float* __restrict__ w3,
    u16* __restrict__ o0, u16* __restrict__ o1,
    u16* __restrict__ o2, u16* __restrict__ o3) {
  int i = blockIdx.x * 256 + threadIdx.x;
  if (i < 110592) o0[i] = f2bf(w0[i]);   // qkv_w 576x192
  if (i < 36864) {                        // proj_w 192x192, k-permuted
    int n = i / 192, kp = i - n * 192;
    int h = kp >> 5, dp = kp & 31;
    int d = (dp & 1) ? ((dp >> 1) + 16) : (dp >> 1);
    o1[i] = f2bf(w1[n * 192 + h * 32 + d]);
  }
  if (i < 221184) o2[i] = f2bf(w2[i]);   // fc1_w 1152x192
  if (i < 221184) o3[i] = f2bf(w3[i]);   // fc2_w 192x1152
}

// ---------------- bias table [6][64(key m)][64(query r)]; key>=49 -> -1e30 ----
__global__ __launch_bounds__(256) void build_btab(
    const float* __restrict__ rpb, float* __restrict__ btab) {
  int id = blockIdx.x * 256 + threadIdx.x;   // 96*256 = 24576
  int head = id >> 12;
  int m = (id >> 6) & 63;
  int r = id & 63;
  float v;
  if (m >= 49) v = -1e30f;                   // key mask folds into bias
  else if (r >= 49) v = 0.0f;
  else {
    int mi = m / 7, mj = m - mi * 7;
    int ri = r / 7, rj = r - ri * 7;
    v = rpb[((ri - mi + 6) * 13 + (rj - mj + 6)) * 6 + head];
  }
  btab[id] = v;
}

// ---------------- layernorm (fp32 in, bf16 out), 1 wave per row of 192 ----------------
__global__ __launch_bounds__(256) void ln_kernel(
    const float* __restrict__ x, const float* __restrict__ g,
    const float* __restrict__ b, u16* __restrict__ out) {
  int row = blockIdx.x * 4 + (threadIdx.x >> 6);
  int lane = threadIdx.x & 63;
  const float* xr = x + (long)row * 192;
  float e0 = xr[lane], e1 = xr[lane + 64], e2 = xr[lane + 128];
  float s = e0 + e1 + e2;
  #pragma unroll
  for (int o = 1; o < 64; o <<= 1) s += __shfl_xor(s, o);
  float mean = s * (1.0f / 192.0f);
  float d0 = e0 - mean, d1 = e1 - mean, d2 = e2 - mean;
  float q = d0 * d0 + d1 * d1 + d2 * d2;
  #pragma unroll
  for (int o = 1; o < 64; o <<= 1) q += __shfl_xor(q, o);
  float rstd = rsqrtf(q * (1.0f / 192.0f) + 1e-5f);
  u16* orow = out + (long)row * 192;
  orow[lane]       = f2bf(d0 * rstd * g[lane]       + b[lane]);
  orow[lane + 64]  = f2bf(d1 * rstd * g[lane + 64]  + b[lane + 64]);
  orow[lane + 128] = f2bf(d2 * rstd * g[lane + 128] + b[lane + 128]);
}

// ---------------- MFMA GEMM: out[M,N] = A[M,K] @ W[N,K]^T + bias ----------------
// Block tile (MT*32)x96, 4 waves 2x2 (wave tile (MT*16)x48), 16x16x32 bf16 MFMA.
// DOUBLE-BUFFERED K-loop, chunk = 32: stage chunk c+1 into the alternate LDS
// buffer BEFORE computing chunk c; single barrier per chunk (loads overlap MFMA).
// Staging fragment-ordered via global_load_lds width-16 (conflict-free
// ds_read_b128 at lane*8 u16).
//   MT=4: 128-row blocks, LDS 28.7 KB, launch_bounds(256,4) — for large grids.
//   MT=2: 64-row blocks, LDS 25.6 KB, launch_bounds(256,6) — for N=192 GEMMs
//         (grid doubles to ~6 blocks/CU; 24 waves/CU hide the barrier drain).
// Epilogue: 64-row passes through LDS fp32 [64][100] -> coalesced line stores.
// MODE 0: store bf16. MODE 1: fast-GELU -> bf16. MODE 2: +resid(fp32) -> fp32.
// Requires N % 96 == 0, M % (MT*32) == 0, K % 32 == 0.
template<int MODE, int MT>
__global__ __launch_bounds__(256, (MT == 2 ? 6 : 4)) void gemm_kernel(
    const u16* __restrict__ A, const u16* __restrict__ W,
    const float* __restrict__ bias, const float* __restrict__ resid,
    void* __restrict__ out, int N, int K) {
  constexpr int TILES = MT * 2 + 6;          // A tiles + B tiles per buffer
  constexpr int STAGE = TILES * 1024;        // u16, 2 buffers
  __shared__ u16 lds[STAGE > 12800 ? STAGE : 12800];  // overlay 64x100 f32 epilogue
  float* ct = (float*)lds;
  const int tid = threadIdx.x;
  const int wave = tid >> 6, lane = tid & 63;
  const int wm = wave >> 1, wn = wave & 1;
  const int quad = lane >> 4, l15 = lane & 15;
  const long bm = (long)blockIdx.x * (MT * 32);
  const int bn = blockIdx.y * 96;
  const int NC = K >> 5;

  // ---- prologue: stage chunk 0 into buf 0 ----
  for (int t = wave; t < TILES; t += 4) {
    const u16* g = (t < MT * 2)
        ? (A + (bm + t * 16 + l15) * K + quad * 8)
        : (W + (long)(bn + (t - MT * 2) * 16 + l15) * K + quad * 8);
    gld16(g, &lds[t * 512]);
  }
  __syncthreads();

  f32x4 acc[MT][3] = {};
  for (int c = 0; c < NC; c++) {
    const int cur = c & 1;
    if (c + 1 < NC) {
      const int kof = (c + 1) * 32 + quad * 8;
      const int nb = (cur ^ 1) * (TILES * 512);
      for (int t = wave; t < TILES; t += 4) {
        const u16* g = (t < MT * 2)
            ? (A + (bm + t * 16 + l15) * K + kof)
            : (W + (long)(bn + (t - MT * 2) * 16 + l15) * K + kof);
        gld16(g, &lds[nb + t * 512]);
      }
    }
    const u16* buf = lds + cur * (TILES * 512);
    bf16x8 af[MT], bfr[3];
    #pragma unroll
    for (int mt = 0; mt < MT; mt++)
      af[mt] = *(const bf16x8*)&buf[(wm * MT + mt) * 512 + lane * 8];
    #pragma unroll
    for (int nt = 0; nt < 3; nt++)
      bfr[nt] = *(const bf16x8*)&buf[(MT * 2 + wn * 3 + nt) * 512 + lane * 8];
    #pragma unroll
    for (int mt = 0; mt < MT; mt++)
      #pragma unroll
      for (int nt = 0; nt < 3; nt++)
        acc[mt][nt] = __builtin_amdgcn_mfma_f32_16x16x32_bf16(af[mt], bfr[nt], acc[mt][nt], 0, 0, 0);
    __syncthreads();   // drains chunk c+1 staging; guards buf reuse
  }

  // ---- epilogue: 64-row passes through LDS -> coalesced line stores ----
  #pragma unroll
  for (int h = 0; h < MT / 2; h++) {
    if (MT == 2 || wm == h) {
      #pragma unroll
      for (int nt = 0; nt < 3; nt++) {
        int col = wn * 48 + nt * 16 + l15;
        float bi = bias[bn + col];
        #pragma unroll
        for (int mt = 0; mt < MT; mt++) {
          int row0 = (MT == 2 ? wm * 32 : 0) + mt * 16 + quad * 4;
          #pragma unroll
          for (int j = 0; j < 4; j++)
            ct[(row0 + j) * 100 + col] = acc[mt][nt][j] + bi;
        }
      }
    }
    __syncthreads();
    // 64 rows x 24 float4-groups = 1536 chunks, 6 per thread
    #pragma unroll
    for (int it = 0; it < 6; it++) {
      int cc = it * 256 + tid;
      int row = cc / 24, i = cc - row * 24;
      float4 v = *(const float4*)&ct[row * 100 + i * 4];
      long idx = (bm + h * 64 + row) * (long)N + bn + i * 4;
      if (MODE == 2) {
        const float4 rv = *(const float4*)(resid + idx);
        v.x += rv.x; v.y += rv.y; v.z += rv.z; v.w += rv.w;
        *(float4*)((float*)out + idx) = v;
      } else {
        if (MODE == 1) {
          v.x = gelu_f(v.x); v.y = gelu_f(v.y); v.z = gelu_f(v.z); v.w = gelu_f(v.w);
        }
        uint2 pk;
        pk.x = pk2(v.x, v.y);
        pk.y = pk2(v.z, v.w);
        *(uint2*)((u16*)out + idx) = pk;
      }
    }
    if (h + 1 < MT / 2) __syncthreads();
  }
}

// ---------------- MFMA windowed attention: 1 wave per (window, head) ----------------
__global__ __launch_bounds__(256) void attn_kernel(
    const u16* __restrict__ qkv, const float* __restrict__ btab,
    u16* __restrict__ attn) {
  // per-wave u16: P 64x72 = 4608 | Vt 32x72 = 2304 | rsum 64 f32 = 128
  __shared__ u16 lds[4 * 7040];   // 56,320 B
  int tid = threadIdx.x;
  int wave = tid >> 6, lane = tid & 63;
  int quad = lane >> 4, l15 = lane & 15;
  int w = blockIdx.x * 4 + wave;
  int win = w / 6, head = w - win * 6;
  int b = win >> 6, wy = (win >> 3) & 7, wx = win & 7;
  u16* lp = lds + wave * 7040;
  u16* lvt = lp + 4608;
  float* rsum = (float*)(lp + 6912);

  bf16x8 qb[4], ka[4];
  #pragma unroll
  for (int t = 0; t < 4; t++) {
    int n = t * 16 + l15;
    uint4 qv = {0, 0, 0, 0}, kv = {0, 0, 0, 0}, vv = {0, 0, 0, 0};
    if (n < 49) {
      int i = n / 7, j = n - i * 7;
      int y = wy * 7 + i + 3;  if (y >= 56) y -= 56;
      int xx = wx * 7 + j + 3; if (xx >= 56) xx -= 56;
      long base = ((long)(b * 3136 + y * 56 + xx)) * 576 + head * 32 + quad * 8;
      qv = *(const uint4*)(qkv + base);
      kv = *(const uint4*)(qkv + base + 192);
      vv = *(const uint4*)(qkv + base + 384);
    }
    qb[t] = *(const bf16x8*)&qv;
    ka[t] = *(const bf16x8*)&kv;
    const u16* vp = (const u16*)&vv;
    #pragma unroll
    for (int d = 0; d < 8; d++) lvt[(quad * 8 + d) * 72 + n] = vp[d];
  }

  f32x4 s[4][4];
  const f32x4 fz = {0.0f, 0.0f, 0.0f, 0.0f};
  #pragma unroll
  for (int tm = 0; tm < 4; tm++)
    #pragma unroll
    for (int tr = 0; tr < 4; tr++)
      s[tm][tr] = __builtin_amdgcn_mfma_f32_16x16x32_bf16(ka[tm], qb[tr], fz, 0, 0, 0);

  const float scale = 0.17677669529663687f;  // 32^-0.5
  const float* bt = btab + head * 4096;
  float mx[4] = {-1e30f, -1e30f, -1e30f, -1e30f};
  #pragma unroll
  for (int tm = 0; tm < 4; tm++) {
    int m0 = tm * 16 + quad * 4;
    #pragma unroll
    for (int tr = 0; tr < 4; tr++) {
      int r = tr * 16 + l15;
      #pragma unroll
      for (int j = 0; j < 4; j++) {
        float v = s[tm][tr][j] * scale + bt[(m0 + j) * 64 + r];
        s[tm][tr][j] = v;
        mx[tr] = fmaxf(mx[tr], v);
      }
    }
  }
  #pragma unroll
  for (int tr = 0; tr < 4; tr++) {
    mx[tr] = fmaxf(mx[tr], __shfl_xor(mx[tr], 16));
    mx[tr] = fmaxf(mx[tr], __shfl_xor(mx[tr], 32));
  }
  float sm[4] = {0.f, 0.f, 0.f, 0.f};
  #pragma unroll
  for (int tm = 0; tm < 4; tm++) {
    #pragma unroll
    for (int tr = 0; tr < 4; tr++) {
      int r = tr * 16 + l15;
      float e0 = __expf(s[tm][tr][0] - mx[tr]);
      float e1 = __expf(s[tm][tr][1] - mx[tr]);
      float e2 = __expf(s[tm][tr][2] - mx[tr]);
      float e3 = __expf(s[tm][tr][3] - mx[tr]);
      sm[tr] += (e0 + e1) + (e2 + e3);
      uint2 pk;
      pk.x = pk2(e0, e1);
      pk.y = pk2(e2, e3);
      *(uint2*)&lp[r * 72 + tm * 16 + quad * 4] = pk;
    }
  }
  #pragma unroll
  for (int tr = 0; tr < 4; tr++) {
    sm[tr] += __shfl_xor(sm[tr], 16);
    sm[tr] += __shfl_xor(sm[tr], 32);
  }
  if (quad == 0) {
    #pragma unroll
    for (int tr = 0; tr < 4; tr++) rsum[tr * 16 + l15] = __builtin_amdgcn_rcpf(sm[tr]);
  }

  f32x4 o[4][2] = {};
  #pragma unroll
  for (int ks = 0; ks < 2; ks++) {
    bf16x8 vb0 = *(const bf16x8*)&lvt[(l15) * 72 + ks * 32 + quad * 8];
    bf16x8 vb1 = *(const bf16x8*)&lvt[(16 + l15) * 72 + ks * 32 + quad * 8];
    #pragma unroll
    for (int rt = 0; rt < 4; rt++) {
      bf16x8 pf = *(const bf16x8*)&lp[(rt * 16 + l15) * 72 + ks * 32 + quad * 8];
      o[rt][0] = __builtin_amdgcn_mfma_f32_16x16x32_bf16(pf, vb0, o[rt][0], 0, 0, 0);
      o[rt][1] = __builtin_amdgcn_mfma_f32_16x16x32_bf16(pf, vb1, o[rt][1], 0, 0, 0);
    }
  }
  #pragma unroll
  for (int rt = 0; rt < 4; rt++) {
    #pragma unroll
    for (int j = 0; j < 4; j++) {
      int r = rt * 16 + quad * 4 + j;
      if (r < 49) {
        float inv = rsum[r];
        int i = r / 7, jj = r - i * 7;
        int y = wy * 7 + i + 3;   if (y >= 56) y -= 56;
        int xx = wx * 7 + jj + 3; if (xx >= 56) xx -= 56;
        long base = ((long)(b * 3136 + y * 56 + xx)) * 192 + head * 32 + 2 * l15;
        *(unsigned int*)&attn[base] = pk2(o[rt][0][j] * inv, o[rt][1][j] * inv);
      }
    }
  }
}

extern "C" void kernel_launch(void* const* d_in, const int* in_sizes, int n_in,
                              void* d_out, int out_size, void* d_ws, size_t ws_size,
                              hipStream_t stream) {
  (void)in_sizes; (void)n_in; (void)out_size; (void)ws_size;
  const float* x      = (const float*)d_in[0];
  const float* ln1_g  = (const float*)d_in[3];
  const float* ln1_b  = (const float*)d_in[4];
  const float* qkv_w  = (const float*)d_in[5];
  const float* qkv_b  = (const float*)d_in[6];
  const float* rpb    = (const float*)d_in[7];
  const float* proj_w = (const float*)d_in[8];
  const float* proj_b = (const float*)d_in[9];
  const float* ln2_g  = (const float*)d_in[10];
  const float* ln2_b  = (const float*)d_in[11];
  const float* fc1_w  = (const float*)d_in[12];
  const float* fc1_b  = (const float*)d_in[13];
  const float* fc2_w  = (const float*)d_in[14];
  const float* fc2_b  = (const float*)d_in[15];

  // workspace layout (bytes), M=50176:
  //   [0,            38,535,168)  x2 fp32
  //   [38,535,168,   57,802,752)  hA bf16 (ln1 out / ln2 out; btab overlays)
  //   [57,802,752,  115,605,504)  qkv bf16  --+ dead after proj; hid bf16
  //   [115,605,504, 134,873,088)  attn bf16 --+ overlays [57,802,752, ...)
  //   [173,408,256, 174,587,904)  bf16 weights
  char* ws = (char*)d_ws;
  float* x2   = (float*)(ws + 0);
  u16* hA     = (u16*)(ws + 38535168);
  float* btab = (float*)(ws + 38535168);   // live only qkv->attn
  u16* qkv    = (u16*)(ws + 57802752);
  u16* attn   = (u16*)(ws + 115605504);
  u16* hid    = (u16*)(ws + 57802752);
  u16* wbuf   = (u16*)(ws + 173408256);
  u16* qkv_wb  = wbuf;
  u16* proj_wb = wbuf + 110592;
  u16* fc1_wb  = wbuf + 147456;
  u16* fc2_wb  = wbuf + 368640;

  cast_weights<<<dim3(864), 256, 0, stream>>>(qkv_w, proj_w, fc1_w, fc2_w,
                                              qkv_wb, proj_wb, fc1_wb, fc2_wb);
  ln_kernel<<<dim3(12544), 256, 0, stream>>>(x, ln1_g, ln1_b, hA);
  gemm_kernel<0, 4><<<dim3(392, 6), 256, 0, stream>>>(hA, qkv_wb, qkv_b, nullptr,
                                                      qkv, 576, 192);
  build_btab<<<dim3(96), 256, 0, stream>>>(rpb, btab);
  attn_kernel<<<dim3(1536), 256, 0, stream>>>(qkv, btab, attn);
  gemm_kernel<2, 2><<<dim3(784, 2), 256, 0, stream>>>(attn, proj_wb, proj_b, x,
                                                      x2, 192, 192);
  ln_kernel<<<dim3(12544), 256, 0, stream>>>(x2, ln2_g, ln2_b, hA);
  gemm_kernel<1, 4><<<dim3(392, 12), 256, 0, stream>>>(hA, fc1_wb, fc1_b, nullptr,
                                                       hid, 1152, 192);
  gemm_kernel<2, 2><<<dim3(784, 2), 256, 0, stream>>>(hid, fc2_wb, fc2_b, x2,
                                                      (float*)d_out, 192, 1152);
}